// Round 1
// 313.640 us; speedup vs baseline: 1.0018x; 1.0018x over previous
//
#include <hip/hip_runtime.h>
#include <hip/hip_bf16.h>
#include <stdint.h>

// ---------------------------------------------------------------------------
// fp32 inputs; mask int32; fp32 output. Internal pipeline bf16/f16.
// LayerNorm -> fused {q,kv} proj GEMMs with l2norm epilogues (V emitted f16
//   TRANSPOSED [b,h][d][token] with null token baked at col 0)
//   -> flash attn: S^T = K.Q^T (16x16x32 bf16) with PERMUTED K-token rows so
//      exp(S^T) packs straight into the A-operand of 16x16x32 f16 PV MFMAs;
//      mask applied as 0/-512 bias in the QK C-initializer -> out proj.
// R10: V marshalling removed from attn. V^T global layout lets V stage via
//      global_load_lds with the same XOR-granule swizzle as K (pre-swizzled
//      global source, linear LDS dest) and be read as ONE ds_read_b128 per
//      PV fragment. Deletes vPrefetch/vCommit (the 4-way ds_write bank
//      conflict: rows d,d+16 collided at stride 34), halves V LDS reads,
//      and drops to ONE __syncthreads per tile (bias double-buffered).
//      Workspace re-packed to ~70.1 MiB (<= previous 72.01): K de-interleaved
//      to [tok][1024]; WqT overlapped into VtG tail (dead before VtG writes).
// ---------------------------------------------------------------------------

using f32x4  = __attribute__((ext_vector_type(4))) float;
using bf16x8 = __attribute__((ext_vector_type(8))) __bf16;
using f16x8  = __attribute__((ext_vector_type(8))) _Float16;
using uintv4 = __attribute__((ext_vector_type(4))) unsigned int;

__device__ __forceinline__ float b2f(unsigned short u) {
    return __uint_as_float(((unsigned)u) << 16);
}
__device__ __forceinline__ unsigned short f2b(float f) {
    unsigned u = __float_as_uint(f);
    u += 0x7fffu + ((u >> 16) & 1u);   // RNE
    return (unsigned short)(u >> 16);
}
__device__ __forceinline__ f32x4 mfma16(bf16x8 a, bf16x8 b, f32x4 c) {
    return __builtin_amdgcn_mfma_f32_16x16x32_bf16(a, b, c, 0, 0, 0);
}
__device__ __forceinline__ f32x4 mfma16h(f16x8 a, f16x8 b, f32x4 c) {
    return __builtin_amdgcn_mfma_f32_16x16x32_f16(a, b, c, 0, 0, 0);
}
// packed f32x2 -> f16x2 (RTZ), returned as the raw 32-bit pattern
__device__ __forceinline__ unsigned pk16(float a, float b) {
    return __builtin_bit_cast(unsigned, __builtin_amdgcn_cvt_pkrtz(a, b));
}
// async global->LDS, 16B/lane; LDS dst = wave-uniform base + lane*16
__device__ __forceinline__ void gl_lds16(const void* g, void* l) {
    __builtin_amdgcn_global_load_lds(
        (const __attribute__((address_space(1))) unsigned int*)g,
        (__attribute__((address_space(3))) unsigned int*)l, 16, 0, 0);
}

// ------------- weight transpose + fp32->bf16: in[R][C] -> out[C][R] --------
__global__ __launch_bounds__(256) void transpose_f2b(
    const float* __restrict__ in, unsigned short* __restrict__ out,
    int R, int C)
{
    __shared__ unsigned short t[32][33];
    int tx = threadIdx.x, ty = threadIdx.y;       // (32,8)
    int c = blockIdx.x * 32 + tx;
#pragma unroll
    for (int i = 0; i < 4; ++i) {
        int r = blockIdx.y * 32 + ty + i * 8;
        t[ty + i * 8][tx] = f2b(in[(size_t)r * C + c]);
    }
    __syncthreads();
    int r2 = blockIdx.y * 32 + tx;
#pragma unroll
    for (int i = 0; i < 4; ++i) {
        int c2 = blockIdx.x * 32 + ty + i * 8;
        out[(size_t)c2 * R + r2] = t[tx][ty + i * 8];
    }
}

// -------- LayerNorm: one row (1024 fp32) per block of 256 -> bf16 ----------
__global__ __launch_bounds__(256) void ln_kernel(
    const float* __restrict__ x, const float* __restrict__ gamma,
    unsigned short* __restrict__ xn)
{
    int row = blockIdx.x, tid = threadIdx.x;
    int wave = tid >> 6, lane = tid & 63;
    float4 raw = *(const float4*)(x + ((size_t)row << 10) + (tid << 2));
    float v[4] = { raw.x, raw.y, raw.z, raw.w };
    float s  = v[0] + v[1] + v[2] + v[3];
    float s2 = v[0]*v[0] + v[1]*v[1] + v[2]*v[2] + v[3]*v[3];
#pragma unroll
    for (int off = 1; off < 64; off <<= 1) {
        s  += __shfl_xor(s, off);
        s2 += __shfl_xor(s2, off);
    }
    __shared__ float ps[4], ps2[4], sh[2];
    if (lane == 0) { ps[wave] = s; ps2[wave] = s2; }
    __syncthreads();
    if (tid == 0) {
        float S  = ps[0] + ps[1] + ps[2] + ps[3];
        float S2 = ps2[0] + ps2[1] + ps2[2] + ps2[3];
        float mu  = S * (1.f / 1024.f);
        float var = S2 * (1.f / 1024.f) - mu * mu;
        sh[0] = mu; sh[1] = rsqrtf(var + 1e-5f);
    }
    __syncthreads();
    float mu = sh[0], rstd = sh[1];
    float4 g4 = *(const float4*)(gamma + (tid << 2));
    float g[4] = { g4.x, g4.y, g4.z, g4.w };
    unsigned short o[4];
#pragma unroll
    for (int i = 0; i < 4; ++i) o[i] = f2b((v[i] - mu) * rstd * g[i]);
    uint2 out;
    out.x = (unsigned)o[0] | ((unsigned)o[1] << 16);
    out.y = (unsigned)o[2] | ((unsigned)o[3] << 16);
    *(uint2*)(xn + ((size_t)row << 10) + (tid << 2)) = out;
}

// ---- GEMM C[M,N]=A[M,K]*Bt[N,K]^T, 128x128, gl_lds staging, fused epilog --
// MODE 0 (QNORM): per-head l2norm rows + q_scale*0.125*log2e, bf16 out
// MODE 1 (KV):    cols<1024: l2norm + k_scale, bf16 -> Cout (ldc=1024);
//                 cols>=1024: raw f16 TRANSPOSED -> Vout[b*16+h][d][tok+1]
//                 (row stride 2056 halfs)
// MODE 2 (F32):   plain f32 store
template<int MODE>
__global__ __launch_bounds__(256, 2) void gemm_bt(
    const unsigned short* __restrict__ A, const unsigned short* __restrict__ Bt,
    void* __restrict__ Cout, const float* __restrict__ scale,
    unsigned short* __restrict__ Vout,
    int M, int N, int K, int ldc)
{
    __shared__ __bf16 As[128 * 32];
    __shared__ __bf16 Bs[128 * 32];
    int tid = threadIdx.x, lane = tid & 63, wave = tid >> 6;
    int quad = lane >> 4, l15 = lane & 15;
    int m0 = blockIdx.y * 128, n0 = blockIdx.x * 128;
    int wm = (wave & 1) * 64, wn = (wave >> 1) * 64;
    f32x4 acc[4][4] = {};

    const int srow = wave * 32 + (lane >> 2);
    const int scol = (lane & 3) << 3;
    const unsigned short* gA = A  + (size_t)(m0 + srow) * K + scol;
    const unsigned short* gB = Bt + (size_t)(n0 + srow) * K + scol;
    __bf16* lA0 = &As[(wave * 32) * 32];
    __bf16* lA1 = &As[(wave * 32 + 16) * 32];
    __bf16* lB0 = &Bs[(wave * 32) * 32];
    __bf16* lB1 = &Bs[(wave * 32 + 16) * 32];
    const size_t rstep = (size_t)16 * K;

    for (int k0 = 0; k0 < K; k0 += 32) {
        gl_lds16(gA,         lA0);
        gl_lds16(gA + rstep, lA1);
        gl_lds16(gB,         lB0);
        gl_lds16(gB + rstep, lB1);
        gA += 32; gB += 32;
        __syncthreads();
        bf16x8 af[4], bfv[4];
#pragma unroll
        for (int i = 0; i < 4; ++i)
            af[i] = *(const bf16x8*)&As[(wm + i * 16 + l15) * 32 + quad * 8];
#pragma unroll
        for (int j = 0; j < 4; ++j)
            bfv[j] = *(const bf16x8*)&Bs[(wn + j * 16 + l15) * 32 + quad * 8];
#pragma unroll
        for (int i = 0; i < 4; ++i)
#pragma unroll
            for (int j = 0; j < 4; ++j)
                acc[i][j] = mfma16(af[i], bfv[j], acc[i][j]);
        __syncthreads();
    }

    if (MODE == 2) {
#pragma unroll
        for (int i = 0; i < 4; ++i)
#pragma unroll
            for (int j = 0; j < 4; ++j) {
                int row = m0 + wm + i * 16 + quad * 4;
                int col = n0 + wn + j * 16 + l15;
                size_t base = (size_t)row * ldc + col;
#pragma unroll
                for (int r = 0; r < 4; ++r)
                    ((float*)Cout)[base + (size_t)r * ldc] = acc[i][j][r];
            }
        return;
    }

    // wave's 64 cols (wn + j*16 + l15) = exactly one head; head-dim = j*16+l15
    const bool isv = (MODE == 1) && ((n0 + wn) >= 1024);
    if (MODE == 1 && isv) {
        // transposed V store: Vout[(b*16+h)*64 + d][tok+1], f16
        int hv = (n0 + wn - 1024) >> 6;
#pragma unroll
        for (int i = 0; i < 4; ++i)
#pragma unroll
            for (int r = 0; r < 4; ++r) {
                int tok = m0 + wm + i * 16 + quad * 4 + r;
                int b = tok >> 11;
                int col = (tok & 2047) + 1;
                size_t rowb = (size_t)(((b << 4) + hv) << 6);
#pragma unroll
                for (int j = 0; j < 4; ++j) {
                    float v = acc[i][j][r];
                    Vout[(rowb + j * 16 + l15) * 2056 + col] =
                        __builtin_bit_cast(unsigned short, (_Float16)v);
                }
            }
        return;
    }

    float sc[4];
#pragma unroll
    for (int j = 0; j < 4; ++j) {
        float s = scale[j * 16 + l15];
        sc[j] = (MODE == 0) ? s * (0.125f * 1.44269504088896f) : s;
    }
#pragma unroll
    for (int i = 0; i < 4; ++i)
#pragma unroll
        for (int r = 0; r < 4; ++r) {
            float ss = 0.f;
#pragma unroll
            for (int j = 0; j < 4; ++j) ss += acc[i][j][r] * acc[i][j][r];
            ss += __shfl_xor(ss, 1); ss += __shfl_xor(ss, 2);
            ss += __shfl_xor(ss, 4); ss += __shfl_xor(ss, 8);
            float mul = rsqrtf(ss + 1e-12f);
            size_t rowbase = (size_t)(m0 + wm + i * 16 + quad * 4 + r) * ldc
                           + n0 + wn + l15;
#pragma unroll
            for (int j = 0; j < 4; ++j) {
                float v = acc[i][j][r];
                ((unsigned short*)Cout)[rowbase + j * 16] = f2b(v * mul * sc[j]);
            }
        }
}

// -- null kv: l2norm k + k_scale (bf16); v -> VtG col 0; zero VtG pad cols --
// Runs AFTER gemm<0> (WqT, overlapped into VtG tail, is dead by then) and
// BEFORE gemm<1> (which writes VtG cols 1..2048, incl. overwriting col 2048
// of the zeroed granule with real data).
__global__ __launch_bounds__(256) void nullkv_kernel(
    const float* __restrict__ null_kv, const float* __restrict__ k_scale,
    unsigned short* __restrict__ knull, unsigned short* __restrict__ Vt)
{
    int wave = threadIdx.x >> 6, lane = threadIdx.x & 63;
    int h = blockIdx.x * 4 + wave;
    int idx = (h << 6) + lane;
    float kvl = null_kv[idx];
    float ss = kvl * kvl;
#pragma unroll
    for (int off = 1; off < 64; off <<= 1) ss += __shfl_xor(ss, off);
    knull[idx] = f2b(kvl * rsqrtf(ss + 1e-12f) * k_scale[lane]);
    unsigned short vn =
        __builtin_bit_cast(unsigned short, (_Float16)null_kv[1024 + idx]);
#pragma unroll
    for (int b = 0; b < 4; ++b)
        Vt[((size_t)(((b << 4) + h) << 6) + lane) * 2056] = vn;
    // zero pad cols 2048..2055 of all 4096 rows (16B aligned at byte 4096)
    int t = blockIdx.x * 256 + threadIdx.x;        // 0..1023
    uintv4 z = { 0u, 0u, 0u, 0u };
#pragma unroll
    for (int rr = 0; rr < 4; ++rr) {
        size_t row = (size_t)t * 4 + rr;
        *(uintv4*)(Vt + row * 2056 + 2048) = z;
    }
}

// ---------------- attention: BM=128 (4 waves x 32 rows), BT=64 tokens ------
// K rows staged PERMUTED: LDS row r holds physical token T(r) so that the
// C-layouts of S^T tiles (2g,2g+1) form the A-operand of 16x16x32 f16 PV:
//   T(r) = 32*(r>>5) + 8*((r>>2)&3) + 4*((r>>4)&1) + (r&3)
//   => A k-slot (quad*8+j) holds physical token 32g + 8*quad + j.
// V staged from VtG [bh][d][tok] via gl_lds with the SAME XOR-granule
// swizzle as K (slot w holds source granule w^(d&7)); each PV B-fragment is
// one conflict-free ds_read_b128 (tokens g*32+quad*8..+7 contiguous in row).
// Mask enters as 0/-512 bias via the QK C-initializer (exp2(-512)=0), bias
// double-buffered in LDS -> ONE __syncthreads per tile.
__global__ __launch_bounds__(256, 3) void attn_kernel(
    const unsigned short* __restrict__ qn,    // [B*2048,1024] l2norm*qs*log2e/8
    const unsigned short* __restrict__ kvK,   // [B*2048,1024] k bf16 (l2norm)
    const unsigned short* __restrict__ knull, // [16*64] bf16
    const unsigned short* __restrict__ Vt,    // [64bh][64d][2056tok] f16
    const int* __restrict__ mask,             // [B*2048]
    unsigned short* __restrict__ ao)          // [B*2048,1024]
{
    __shared__ __bf16    Kt[2][64 * 64];
    __shared__ _Float16  Vl[2][64 * 64];
    __shared__ __align__(16) float biasLds[2][64];

    const int tid = threadIdx.x, lane = tid & 63, wave = tid >> 6;
    const int quad = lane >> 4, l15 = lane & 15;
    const int bh = blockIdx.x;                 // (b,h): K/V sharers same XCD
    const int b = bh >> 4, h = bh & 15;
    const int mbase = blockIdx.y * 128 + wave * 32;
    const size_t rowoff = (size_t)b * 2048;

    bf16x8 qf[2][2];                           // B-operand fragments
#pragma unroll
    for (int rg = 0; rg < 2; ++rg)
#pragma unroll
        for (int ks = 0; ks < 2; ++ks)
            qf[rg][ks] = *(const bf16x8*)
                &qn[((rowoff + mbase + rg * 16 + l15) << 10) + (h << 6) + ks * 32 + quad * 8];

    const int t8  = lane >> 3;
    const int w7  = lane & 7;
    const int ksc = (w7 ^ t8) << 3;            // (r&7)==t8 since base%8==0
    const size_t vrow0 = ((size_t)bh << 6);    // first VtG row of this (b,h)

    auto kIssue = [&](int nt, int buf) {
#pragma unroll
        for (int p = 0; p < 2; ++p) {
            int r = wave * 16 + p * 8 + t8;
            int T = ((r >> 5) << 5) | (((r >> 2) & 3) << 3)
                  | (((r >> 4) & 1) << 2) | (r & 3);
            int j = (nt << 6) + T;
            int jr = j - 1; if (jr > 2047) jr = 2047;
            const unsigned short* src = (j == 0)
                ? knull + (h << 6) + ksc
                : kvK + ((rowoff + (size_t)jr) << 10) + (h << 6) + ksc;
            gl_lds16(src, &Kt[buf][(wave * 16 + p * 8) * 64]);
        }
    };
    auto vIssue = [&](int nt, int buf) {
#pragma unroll
        for (int p = 0; p < 2; ++p) {
            int d = wave * 16 + p * 8 + t8;
            int gsrc = (nt << 3) + (w7 ^ t8);  // source granule within row
            if (gsrc > 256) gsrc = 256;        // tail: cols 2049+ are weight-0
            const unsigned short* src = Vt + (vrow0 + d) * 2056 + (gsrc << 3);
            gl_lds16(src, &Vl[buf][(wave * 16 + p * 8) * 64]);
        }
    };
    auto biasFor = [&](int nt) -> float {
        int j = (nt << 6) + tid;               // only tid<64 consumed
        float bv = -512.f;
        if (j == 0 || (j <= 2048 && mask[b * 2048 + j - 1] != 0)) bv = 0.f;
        return bv;
    };

    f32x4 O[2][4] = {};
    float rs[2] = {0.f, 0.f};

    kIssue(0, 0);
    vIssue(0, 0);
    float bcur = biasFor(0);

    for (int nt = 0; nt < 33; ++nt) {
        const int buf = nt & 1;
        if (tid < 64) biasLds[buf][tid] = bcur;
        __syncthreads();   // drains gl_lds(nt); bias(nt) visible; prev buf free
        if (nt < 32) {     // issue AFTER barrier: overlaps compute below
            kIssue(nt + 1, buf ^ 1);
            vIssue(nt + 1, buf ^ 1);
            bcur = biasFor(nt + 1);
        }

#pragma unroll
        for (int g = 0; g < 2; ++g) {
            // --- QK^T: only one kf pair (8 VGPRs) live at a time ---
            float4 b0 = *(const float4*)&biasLds[buf][(g << 5) + (quad << 3)];
            float4 b1 = *(const float4*)&biasLds[buf][(g << 5) + (quad << 3) + 4];
            f32x4 s[2][2];
#pragma unroll
            for (int rg = 0; rg < 2; ++rg) {
                s[rg][0] = f32x4{ b0.x, b0.y, b0.z, b0.w };
                s[rg][1] = f32x4{ b1.x, b1.y, b1.z, b1.w };
            }
#pragma unroll
            for (int t = 0; t < 2; ++t) {
                const __bf16* kb = &Kt[buf][((g * 2 + t) * 16 + l15) * 64];
                bf16x8 k0 = *(const bf16x8*)&kb[(quad ^ (l15 & 7)) << 3];
                bf16x8 k1 = *(const bf16x8*)&kb[((4 + quad) ^ (l15 & 7)) << 3];
#pragma unroll
                for (int rg = 0; rg < 2; ++rg) {
                    s[rg][t] = mfma16(k0, qf[rg][0], s[rg][t]);
                    s[rg][t] = mfma16(k1, qf[rg][1], s[rg][t]);
                }
            }
            // --- V fragments: one b128 each, XOR-swizzled slot ---
            f16x8 vf8[4];
#pragma unroll
            for (int dt = 0; dt < 4; ++dt)
                vf8[dt] = *(const f16x8*)
                    &Vl[buf][(dt * 16 + l15) * 64
                             + ((((g << 2) + quad) ^ (l15 & 7)) << 3)];
            // --- exp2 + pack + PV ---
#pragma unroll
            for (int rg = 0; rg < 2; ++rg) {
                float e0 = __builtin_amdgcn_exp2f(s[rg][0][0]);
                float e1 = __builtin_amdgcn_exp2f(s[rg][0][1]);
                float e2 = __builtin_amdgcn_exp2f(s[rg][0][2]);
                float e3 = __builtin_amdgcn_exp2f(s[rg][0][3]);
                float e4 = __builtin_amdgcn_exp2f(s[rg][1][0]);
                float e5 = __builtin_amdgcn_exp2f(s[rg][1][1]);
                float e6 = __builtin_amdgcn_exp2f(s[rg][1][2]);
                float e7 = __builtin_amdgcn_exp2f(s[rg][1][3]);
                rs[rg] += ((e0 + e1) + (e2 + e3)) + ((e4 + e5) + (e6 + e7));
                uintv4 pu = { pk16(e0, e1), pk16(e2, e3),
                              pk16(e4, e5), pk16(e6, e7) };
                f16x8 p = __builtin_bit_cast(f16x8, pu);
#pragma unroll
                for (int dt = 0; dt < 4; ++dt)
                    O[rg][dt] = mfma16h(p, vf8[dt], O[rg][dt]);
            }
        }
    }

    // rs: lane(quad,l15) holds partial for q=l15 -> sum across quads
#pragma unroll
    for (int rg = 0; rg < 2; ++rg) {
        rs[rg] += __shfl_xor(rs[rg], 16);
        rs[rg] += __shfl_xor(rs[rg], 32);
    }
#pragma unroll
    for (int rg = 0; rg < 2; ++rg) {
        float inv[4];
#pragma unroll
        for (int r = 0; r < 4; ++r)
            inv[r] = 1.f / __shfl(rs[rg], quad * 4 + r);   // q = rg*16+quad*4+r
#pragma unroll
        for (int dt = 0; dt < 4; ++dt) {
            size_t base = ((rowoff + mbase + rg * 16 + quad * 4) << 10)
                        + (h << 6) + dt * 16 + l15;
#pragma unroll
            for (int r = 0; r < 4; ++r)
                ao[base + ((size_t)r << 10)] = f2b(O[rg][dt][r] * inv[r]);
        }
    }
}

// ---------------------------------------------------------------------------
extern "C" void kernel_launch(void* const* d_in, const int* in_sizes, int n_in,
                              void* d_out, int out_size, void* d_ws, size_t ws_size,
                              hipStream_t stream)
{
    const float* x       = (const float*)d_in[0];
    const int*   mask    = (const int*)d_in[1];
    const float* gamma   = (const float*)d_in[2];
    const float* null_kv = (const float*)d_in[3];
    const float* Wq      = (const float*)d_in[4];
    const float* Wkv     = (const float*)d_in[5];
    const float* q_scale = (const float*)d_in[6];
    const float* k_scale = (const float*)d_in[7];
    const float* Wout    = (const float*)d_in[8];

    // Workspace map (~70.07 MiB; ao aliases xn; WqT overlaps VtG tail --
    // WqT is dead after gemm<0>, before nullkv/gemm<1> write VtG):
    //   0        xn/ao   16 MiB
    //   16 MiB   q       16 MiB
    //   32 MiB   kvK     16 MiB   [tok][1024] bf16
    //   48 MiB   VtG     16.06 MiB = 4096 rows * 4112 B ([bh][d][2056] f16)
    //   VtGend-2MiB WqT  2 MiB    (inside VtG tail)
    //   VtGend   WkvT    4 MiB
    //   +4 MiB   WoutT   2 MiB
    //   +2 MiB   knull   2 KiB
    char* ws = (char*)d_ws;
    const size_t VTG_OFF  = (size_t)48u << 20;
    const size_t VTG_SIZE = (size_t)4096 * 4112;
    unsigned short* xn    = (unsigned short*)(ws);
    unsigned short* ao    = xn;                                    // reuse
    unsigned short* q     = (unsigned short*)(ws + ((size_t)16u << 20));
    unsigned short* kvK   = (unsigned short*)(ws + ((size_t)32u << 20));
    unsigned short* VtG   = (unsigned short*)(ws + VTG_OFF);
    unsigned short* WqT   = (unsigned short*)(ws + VTG_OFF + VTG_SIZE - ((size_t)2u << 20));
    unsigned short* WkvT  = (unsigned short*)(ws + VTG_OFF + VTG_SIZE);
    unsigned short* WoutT = (unsigned short*)(ws + VTG_OFF + VTG_SIZE + ((size_t)4u << 20));
    unsigned short* knull = (unsigned short*)(ws + VTG_OFF + VTG_SIZE + ((size_t)6u << 20));

    dim3 tb(32, 8);
    transpose_f2b<<<dim3(32, 32), tb, 0, stream>>>(Wq,   WqT,   1024, 1024);
    transpose_f2b<<<dim3(64, 32), tb, 0, stream>>>(Wkv,  WkvT,  1024, 2048);
    transpose_f2b<<<dim3(32, 32), tb, 0, stream>>>(Wout, WoutT, 1024, 1024);

    ln_kernel<<<8192, 256, 0, stream>>>(x, gamma, xn);

    gemm_bt<0><<<dim3(8, 64),  256, 0, stream>>>(xn, WqT, q, q_scale, nullptr,
                                                 8192, 1024, 1024, 1024);
    // nullkv after gemm<0> (WqT dead), before gemm<1> (VtG col 2048 overwrite)
    nullkv_kernel<<<4, 256, 0, stream>>>(null_kv, k_scale, knull, VtG);

    gemm_bt<1><<<dim3(16, 64), 256, 0, stream>>>(xn, WkvT, kvK, k_scale, VtG,
                                                 8192, 2048, 1024, 1024);

    attn_kernel<<<dim3(64, 16), 256, 0, stream>>>(q, kvK, knull, VtG, mask, ao);

    gemm_bt<2><<<dim3(8, 64), 256, 0, stream>>>(ao, WoutT, d_out, nullptr, nullptr,
                                                8192, 1024, 1024, 1024);
}

// Round 2
// 299.759 us; speedup vs baseline: 1.0482x; 1.0463x over previous
//
#include <hip/hip_runtime.h>
#include <hip/hip_bf16.h>
#include <stdint.h>

// ---------------------------------------------------------------------------
// fp32 inputs; mask int32; fp32 output. Internal pipeline bf16/f16.
// LayerNorm -> fused {q,kv} proj GEMMs with l2norm epilogues (V emitted f16
//   TRANSPOSED [b,h][d][token], null token at column 2048, zero pad 2049..55)
//   -> flash attn: S^T = K.Q^T (16x16x32 bf16) with PERMUTED K-token rows so
//      exp(S^T) packs straight into the A-operand of 16x16x32 f16 PV MFMAs;
//      mask applied as 0/-512 bias in the QK C-initializer -> out proj.
// R11: attn is VALU-issue-bound (VALUBusy 43 vs MfmaUtil 29). Cuts:
//   (a) null token moved to END (softmax order-invariant) -> tiles 0..31 are
//       branch-free; K/V staging addrs strength-reduced to 4 ptr increments
//       per tile (was ~50 VALU of 64-bit recompute + clamps + selects).
//   (b) softmax denominator via ones-MFMA (4 extra MFMA/tile) replaces 32
//       VALU adds/tile AND the final cross-lane shfl reduction (D-row of
//       rsacc lands on exactly the lane that writes that q-row).
//   (c) bias/mask computed by wave 0 only.
//   (d) gemm<1> V-epilogue: per-wave 64x64 LDS transpose (XOR tok^((d&7)<<3))
//       -> contiguous uint2 global stores (R10 scattered 2B stores at stride
//       4112B were the ~8us hidden regression).
// ---------------------------------------------------------------------------

using f32x4  = __attribute__((ext_vector_type(4))) float;
using bf16x8 = __attribute__((ext_vector_type(8))) __bf16;
using f16x8  = __attribute__((ext_vector_type(8))) _Float16;
using uintv4 = __attribute__((ext_vector_type(4))) unsigned int;

__device__ __forceinline__ float b2f(unsigned short u) {
    return __uint_as_float(((unsigned)u) << 16);
}
__device__ __forceinline__ unsigned short f2b(float f) {
    unsigned u = __float_as_uint(f);
    u += 0x7fffu + ((u >> 16) & 1u);   // RNE
    return (unsigned short)(u >> 16);
}
__device__ __forceinline__ unsigned short f2h(float f) {   // RNE f32->f16
    return __builtin_bit_cast(unsigned short, (_Float16)f);
}
__device__ __forceinline__ f32x4 mfma16(bf16x8 a, bf16x8 b, f32x4 c) {
    return __builtin_amdgcn_mfma_f32_16x16x32_bf16(a, b, c, 0, 0, 0);
}
__device__ __forceinline__ f32x4 mfma16h(f16x8 a, f16x8 b, f32x4 c) {
    return __builtin_amdgcn_mfma_f32_16x16x32_f16(a, b, c, 0, 0, 0);
}
// packed f32x2 -> f16x2 (RTZ), returned as the raw 32-bit pattern
__device__ __forceinline__ unsigned pk16(float a, float b) {
    return __builtin_bit_cast(unsigned, __builtin_amdgcn_cvt_pkrtz(a, b));
}
// async global->LDS, 16B/lane; LDS dst = wave-uniform base + lane*16
__device__ __forceinline__ void gl_lds16(const void* g, void* l) {
    __builtin_amdgcn_global_load_lds(
        (const __attribute__((address_space(1))) unsigned int*)g,
        (__attribute__((address_space(3))) unsigned int*)l, 16, 0, 0);
}

// ------------- weight transpose + fp32->bf16: in[R][C] -> out[C][R] --------
__global__ __launch_bounds__(256) void transpose_f2b(
    const float* __restrict__ in, unsigned short* __restrict__ out,
    int R, int C)
{
    __shared__ unsigned short t[32][33];
    int tx = threadIdx.x, ty = threadIdx.y;       // (32,8)
    int c = blockIdx.x * 32 + tx;
#pragma unroll
    for (int i = 0; i < 4; ++i) {
        int r = blockIdx.y * 32 + ty + i * 8;
        t[ty + i * 8][tx] = f2b(in[(size_t)r * C + c]);
    }
    __syncthreads();
    int r2 = blockIdx.y * 32 + tx;
#pragma unroll
    for (int i = 0; i < 4; ++i) {
        int c2 = blockIdx.x * 32 + ty + i * 8;
        out[(size_t)c2 * R + r2] = t[tx][ty + i * 8];
    }
}

// -------- LayerNorm: one row (1024 fp32) per block of 256 -> bf16 ----------
__global__ __launch_bounds__(256) void ln_kernel(
    const float* __restrict__ x, const float* __restrict__ gamma,
    unsigned short* __restrict__ xn)
{
    int row = blockIdx.x, tid = threadIdx.x;
    int wave = tid >> 6, lane = tid & 63;
    float4 raw = *(const float4*)(x + ((size_t)row << 10) + (tid << 2));
    float v[4] = { raw.x, raw.y, raw.z, raw.w };
    float s  = v[0] + v[1] + v[2] + v[3];
    float s2 = v[0]*v[0] + v[1]*v[1] + v[2]*v[2] + v[3]*v[3];
#pragma unroll
    for (int off = 1; off < 64; off <<= 1) {
        s  += __shfl_xor(s, off);
        s2 += __shfl_xor(s2, off);
    }
    __shared__ float ps[4], ps2[4], sh[2];
    if (lane == 0) { ps[wave] = s; ps2[wave] = s2; }
    __syncthreads();
    if (tid == 0) {
        float S  = ps[0] + ps[1] + ps[2] + ps[3];
        float S2 = ps2[0] + ps2[1] + ps2[2] + ps2[3];
        float mu  = S * (1.f / 1024.f);
        float var = S2 * (1.f / 1024.f) - mu * mu;
        sh[0] = mu; sh[1] = rsqrtf(var + 1e-5f);
    }
    __syncthreads();
    float mu = sh[0], rstd = sh[1];
    float4 g4 = *(const float4*)(gamma + (tid << 2));
    float g[4] = { g4.x, g4.y, g4.z, g4.w };
    unsigned short o[4];
#pragma unroll
    for (int i = 0; i < 4; ++i) o[i] = f2b((v[i] - mu) * rstd * g[i]);
    uint2 out;
    out.x = (unsigned)o[0] | ((unsigned)o[1] << 16);
    out.y = (unsigned)o[2] | ((unsigned)o[3] << 16);
    *(uint2*)(xn + ((size_t)row << 10) + (tid << 2)) = out;
}

// ---- GEMM C[M,N]=A[M,K]*Bt[N,K]^T, 128x128, gl_lds staging, fused epilog --
// MODE 0 (QNORM): per-head l2norm rows + q_scale*0.125*log2e, bf16 out
// MODE 1 (KV):    cols<1024: l2norm + k_scale, bf16 -> Cout (ldc=1024);
//                 cols>=1024: raw f16 TRANSPOSED -> Vout[b*16+h][d][tok]
//                 (row stride 2056 halfs) via per-wave LDS transpose,
//                 contiguous uint2 stores.
// MODE 2 (F32):   plain f32 store
template<int MODE>
__global__ __launch_bounds__(256, 2) void gemm_bt(
    const unsigned short* __restrict__ A, const unsigned short* __restrict__ Bt,
    void* __restrict__ Cout, const float* __restrict__ scale,
    unsigned short* __restrict__ Vout,
    int M, int N, int K, int ldc)
{
    __shared__ __bf16 As[128 * 32];
    __shared__ __bf16 Bs[128 * 32];
    int tid = threadIdx.x, lane = tid & 63, wave = tid >> 6;
    int quad = lane >> 4, l15 = lane & 15;
    int m0 = blockIdx.y * 128, n0 = blockIdx.x * 128;
    int wm = (wave & 1) * 64, wn = (wave >> 1) * 64;
    f32x4 acc[4][4] = {};

    const int srow = wave * 32 + (lane >> 2);
    const int scol = (lane & 3) << 3;
    const unsigned short* gA = A  + (size_t)(m0 + srow) * K + scol;
    const unsigned short* gB = Bt + (size_t)(n0 + srow) * K + scol;
    __bf16* lA0 = &As[(wave * 32) * 32];
    __bf16* lA1 = &As[(wave * 32 + 16) * 32];
    __bf16* lB0 = &Bs[(wave * 32) * 32];
    __bf16* lB1 = &Bs[(wave * 32 + 16) * 32];
    const size_t rstep = (size_t)16 * K;

    for (int k0 = 0; k0 < K; k0 += 32) {
        gl_lds16(gA,         lA0);
        gl_lds16(gA + rstep, lA1);
        gl_lds16(gB,         lB0);
        gl_lds16(gB + rstep, lB1);
        gA += 32; gB += 32;
        __syncthreads();
        bf16x8 af[4], bfv[4];
#pragma unroll
        for (int i = 0; i < 4; ++i)
            af[i] = *(const bf16x8*)&As[(wm + i * 16 + l15) * 32 + quad * 8];
#pragma unroll
        for (int j = 0; j < 4; ++j)
            bfv[j] = *(const bf16x8*)&Bs[(wn + j * 16 + l15) * 32 + quad * 8];
#pragma unroll
        for (int i = 0; i < 4; ++i)
#pragma unroll
            for (int j = 0; j < 4; ++j)
                acc[i][j] = mfma16(af[i], bfv[j], acc[i][j]);
        __syncthreads();
    }

    if (MODE == 2) {
#pragma unroll
        for (int i = 0; i < 4; ++i)
#pragma unroll
            for (int j = 0; j < 4; ++j) {
                int row = m0 + wm + i * 16 + quad * 4;
                int col = n0 + wn + j * 16 + l15;
                size_t base = (size_t)row * ldc + col;
#pragma unroll
                for (int r = 0; r < 4; ++r)
                    ((float*)Cout)[base + (size_t)r * ldc] = acc[i][j][r];
            }
        return;
    }

    // wave's 64 cols (wn + j*16 + l15) = exactly one head; head-dim = j*16+l15
    if constexpr (MODE == 1) {
        const bool isv = (n0 + wn) >= 1024;
        if (isv) {
            // per-wave 64x64 (tok x d) tile -> LDS transposed with XOR
            // swizzle tok^((d&7)<<3) -> contiguous uint2 global stores.
            __shared__ unsigned short Vx[4][64 * 64];   // 32 KB (MODE 1 only)
            unsigned short* tileL = Vx[wave];
            int hv = (n0 + wn - 1024) >> 6;
            int bidx = m0 >> 11;                        // block never straddles
            int tok0w = (m0 + wm) & 2047;
            size_t vbase = (size_t)((((bidx << 4) + hv) << 6)) * 2056;
#pragma unroll
            for (int i = 0; i < 4; ++i)
#pragma unroll
                for (int j = 0; j < 4; ++j) {
                    int d = j * 16 + l15;
                    int tk = (i * 16 + quad * 4) ^ ((d & 7) << 3);
                    unsigned u01 = (unsigned)f2h(acc[i][j][0])
                                 | ((unsigned)f2h(acc[i][j][1]) << 16);
                    unsigned u23 = (unsigned)f2h(acc[i][j][2])
                                 | ((unsigned)f2h(acc[i][j][3]) << 16);
                    *(unsigned*)&tileL[d * 64 + tk]     = u01;
                    *(unsigned*)&tileL[d * 64 + tk + 2] = u23;
                }
            // same-wave read-out (compiler orders via lgkmcnt)
#pragma unroll
            for (int rr = 0; rr < 16; ++rr) {
                int d = rr * 4 + quad;
                uint2 val = *(const uint2*)
                    &tileL[d * 64 + ((l15 * 4) ^ ((d & 7) << 3))];
                *(uint2*)(Vout + vbase + (size_t)d * 2056 + tok0w + l15 * 4) = val;
            }
            return;
        }
    }

    float sc[4];
#pragma unroll
    for (int j = 0; j < 4; ++j) {
        float s = scale[j * 16 + l15];
        sc[j] = (MODE == 0) ? s * (0.125f * 1.44269504088896f) : s;
    }
#pragma unroll
    for (int i = 0; i < 4; ++i)
#pragma unroll
        for (int r = 0; r < 4; ++r) {
            float ss = 0.f;
#pragma unroll
            for (int j = 0; j < 4; ++j) ss += acc[i][j][r] * acc[i][j][r];
            ss += __shfl_xor(ss, 1); ss += __shfl_xor(ss, 2);
            ss += __shfl_xor(ss, 4); ss += __shfl_xor(ss, 8);
            float mul = rsqrtf(ss + 1e-12f);
            size_t rowbase = (size_t)(m0 + wm + i * 16 + quad * 4 + r) * ldc
                           + n0 + wn + l15;
#pragma unroll
            for (int j = 0; j < 4; ++j) {
                float v = acc[i][j][r];
                ((unsigned short*)Cout)[rowbase + j * 16] = f2b(v * mul * sc[j]);
            }
        }
}

// -- null kv: l2norm k + k_scale (bf16); v -> VtG col 2048; zero 2049..2055 -
// Runs AFTER gemm<0> (WqT, overlapped into VtG tail, is dead by then).
__global__ __launch_bounds__(256) void nullkv_kernel(
    const float* __restrict__ null_kv, const float* __restrict__ k_scale,
    unsigned short* __restrict__ knull, unsigned short* __restrict__ Vt)
{
    int wave = threadIdx.x >> 6, lane = threadIdx.x & 63;
    int h = blockIdx.x * 4 + wave;
    int idx = (h << 6) + lane;
    float kvl = null_kv[idx];
    float ss = kvl * kvl;
#pragma unroll
    for (int off = 1; off < 64; off <<= 1) ss += __shfl_xor(ss, off);
    knull[idx] = f2b(kvl * rsqrtf(ss + 1e-12f) * k_scale[lane]);
    unsigned short vn = f2h(null_kv[1024 + idx]);
#pragma unroll
    for (int b = 0; b < 4; ++b)
        Vt[((size_t)(((b << 4) + h) << 6) + lane) * 2056 + 2048] = vn;
    // zero pad cols 2049..2055 of all 4096 rows
    int t = blockIdx.x * 256 + threadIdx.x;        // 0..1023
#pragma unroll
    for (int rr = 0; rr < 4; ++rr) {
        size_t row = (size_t)t * 4 + rr;
#pragma unroll
        for (int c = 0; c < 7; ++c)
            Vt[row * 2056 + 2049 + c] = 0;
    }
}

// ---------------- attention: BM=128 (4 waves x 32 rows), BT=64 tokens ------
// Logical token order = physical: positions 0..2047 real, 2048 null,
// 2049..2055 zero-pad (bias -512 kills them). K rows staged PERMUTED:
//   T(r) = 32*(r>>5) + 8*((r>>2)&3) + 4*((r>>4)&1) + (r&3)
// so exp(S^T) C-layout packs straight into PV's A-operand. V staged from
// VtG [bh][d][tok] via gl_lds with the K-style XOR-granule swizzle; each PV
// B-fragment is one conflict-free ds_read_b128. Tiles 0..31: staging =
// 4 pointer increments (strength-reduced); tile 32 special (null + clamp).
// Softmax denominator via ones-MFMA: rsacc[rg][r] lands on the lane that
// writes q-row quad*4+r -> no cross-lane reduction.
__global__ __launch_bounds__(256, 3) void attn_kernel(
    const unsigned short* __restrict__ qn,    // [B*2048,1024] l2norm*qs*log2e/8
    const unsigned short* __restrict__ kvK,   // [B*2048,1024] k bf16 (l2norm)
    const unsigned short* __restrict__ knull, // [16*64] bf16
    const unsigned short* __restrict__ Vt,    // [64bh][64d][2056tok] f16
    const int* __restrict__ mask,             // [B*2048]
    unsigned short* __restrict__ ao)          // [B*2048,1024]
{
    __shared__ __bf16    Kt[2][64 * 64];
    __shared__ _Float16  Vl[2][64 * 64];
    __shared__ __align__(16) float biasLds[2][64];

    const int tid = threadIdx.x, lane = tid & 63, wave = tid >> 6;
    const int quad = lane >> 4, l15 = lane & 15;
    const int bh = blockIdx.x;                 // (b,h): K/V sharers same XCD
    const int b = bh >> 4, h = bh & 15;
    const int mbase = blockIdx.y * 128 + wave * 32;
    const size_t rowoff = (size_t)b * 2048;

    bf16x8 qf[2][2];                           // B-operand fragments
#pragma unroll
    for (int rg = 0; rg < 2; ++rg)
#pragma unroll
        for (int ks = 0; ks < 2; ++ks)
            qf[rg][ks] = *(const bf16x8*)
                &qn[((rowoff + mbase + rg * 16 + l15) << 10) + (h << 6) + ks * 32 + quad * 8];

    const int t8  = lane >> 3;
    const int w7  = lane & 7;
    const int ksc = (w7 ^ t8) << 3;            // (r&7)==t8 since base%8==0
    const size_t vrow0 = ((size_t)bh << 6);    // first VtG row of this (b,h)

    const int r0v = wave * 16 + t8;            // LDS row (p=0) = V d-row
    const int r1v = wave * 16 + 8 + t8;        // LDS row (p=1)
    auto Tof = [](int r) {
        return ((r >> 5) << 5) | (((r >> 2) & 3) << 3)
             | (((r >> 4) & 1) << 2) | (r & 3);
    };
    const int T0 = Tof(r0v), T1 = Tof(r1v);    // T1 != 0 always

    // strength-reduced staging pointers (point at NEXT tile to issue)
    const unsigned short* kp0 = kvK + ((rowoff + T0) << 10) + (h << 6) + ksc;
    const unsigned short* kp1 = kvK + ((rowoff + T1) << 10) + (h << 6) + ksc;
    const unsigned short* vp0 = Vt + (vrow0 + r0v) * 2056 + ((w7 ^ t8) << 3);
    const unsigned short* vp1 = Vt + (vrow0 + r1v) * 2056 + ((w7 ^ t8) << 3);

    auto issueFast = [&](int bf) {
        gl_lds16(kp0, &Kt[bf][(wave * 16) * 64]);
        gl_lds16(kp1, &Kt[bf][(wave * 16 + 8) * 64]);
        gl_lds16(vp0, &Vl[bf][(wave * 16) * 64]);
        gl_lds16(vp1, &Vl[bf][(wave * 16 + 8) * 64]);
        kp0 += 65536; kp1 += 65536;            // 64 tokens * 1024 halfs
        vp0 += 64; vp1 += 64;                  // 8 granules
    };
    auto issue32 = [&](int bf) {               // tokens 2048..2111
        const unsigned short* kc =
            kvK + ((rowoff + 2047) << 10) + (h << 6) + ksc;   // finite clamp
        const unsigned short* s0 = (T0 == 0) ? knull + (h << 6) + ksc : kc;
        gl_lds16(s0, &Kt[bf][(wave * 16) * 64]);
        gl_lds16(kc, &Kt[bf][(wave * 16 + 8) * 64]);
        gl_lds16(Vt + (vrow0 + r0v) * 2056 + 2048, &Vl[bf][(wave * 16) * 64]);
        gl_lds16(Vt + (vrow0 + r1v) * 2056 + 2048, &Vl[bf][(wave * 16 + 8) * 64]);
    };
    auto biasFor = [&](int nt) -> float {      // wave 0 only
        int j = (nt << 6) + lane;
        float bv = -512.f;
        if (j < 2048) { if (mask[(b << 11) + j] != 0) bv = 0.f; }
        else if (j == 2048) bv = 0.f;
        return bv;
    };

    const uintv4 onesu = { 0x3c003c00u, 0x3c003c00u, 0x3c003c00u, 0x3c003c00u };
    const f16x8 ones = __builtin_bit_cast(f16x8, onesu);

    f32x4 O[2][4] = {};
    f32x4 rsacc[2] = {};

    issueFast(0);
    float bcur = 0.f;
    if (wave == 0) bcur = biasFor(0);

    for (int nt = 0; nt < 33; ++nt) {
        const int buf = nt & 1;
        if (wave == 0) biasLds[buf][lane] = bcur;
        __syncthreads();   // drains gl_lds(nt); bias(nt) visible; prev buf free
        if (nt < 31) {     // issue AFTER barrier: overlaps compute below
            issueFast(buf ^ 1);
            if (wave == 0) bcur = biasFor(nt + 1);
        } else if (nt == 31) {
            issue32(buf ^ 1);
            if (wave == 0) bcur = biasFor(32);
        }

#pragma unroll
        for (int g = 0; g < 2; ++g) {
            // --- QK^T: only one kf pair (8 VGPRs) live at a time ---
            float4 b0 = *(const float4*)&biasLds[buf][(g << 5) + (quad << 3)];
            float4 b1 = *(const float4*)&biasLds[buf][(g << 5) + (quad << 3) + 4];
            f32x4 s[2][2];
#pragma unroll
            for (int rg = 0; rg < 2; ++rg) {
                s[rg][0] = f32x4{ b0.x, b0.y, b0.z, b0.w };
                s[rg][1] = f32x4{ b1.x, b1.y, b1.z, b1.w };
            }
#pragma unroll
            for (int t = 0; t < 2; ++t) {
                const __bf16* kb = &Kt[buf][((g * 2 + t) * 16 + l15) * 64];
                bf16x8 k0 = *(const bf16x8*)&kb[(quad ^ (l15 & 7)) << 3];
                bf16x8 k1 = *(const bf16x8*)&kb[((4 + quad) ^ (l15 & 7)) << 3];
#pragma unroll
                for (int rg = 0; rg < 2; ++rg) {
                    s[rg][t] = mfma16(k0, qf[rg][0], s[rg][t]);
                    s[rg][t] = mfma16(k1, qf[rg][1], s[rg][t]);
                }
            }
            // --- V fragments: one b128 each, XOR-swizzled slot ---
            f16x8 vf8[4];
#pragma unroll
            for (int dt = 0; dt < 4; ++dt)
                vf8[dt] = *(const f16x8*)
                    &Vl[buf][(dt * 16 + l15) * 64
                             + ((((g << 2) + quad) ^ (l15 & 7)) << 3)];
            // --- exp2 + pack + PV (+ denominator via ones-MFMA) ---
#pragma unroll
            for (int rg = 0; rg < 2; ++rg) {
                float e0 = __builtin_amdgcn_exp2f(s[rg][0][0]);
                float e1 = __builtin_amdgcn_exp2f(s[rg][0][1]);
                float e2 = __builtin_amdgcn_exp2f(s[rg][0][2]);
                float e3 = __builtin_amdgcn_exp2f(s[rg][0][3]);
                float e4 = __builtin_amdgcn_exp2f(s[rg][1][0]);
                float e5 = __builtin_amdgcn_exp2f(s[rg][1][1]);
                float e6 = __builtin_amdgcn_exp2f(s[rg][1][2]);
                float e7 = __builtin_amdgcn_exp2f(s[rg][1][3]);
                uintv4 pu = { pk16(e0, e1), pk16(e2, e3),
                              pk16(e4, e5), pk16(e6, e7) };
                f16x8 p = __builtin_bit_cast(f16x8, pu);
                rsacc[rg] = mfma16h(p, ones, rsacc[rg]);
#pragma unroll
                for (int dt = 0; dt < 4; ++dt)
                    O[rg][dt] = mfma16h(p, vf8[dt], O[rg][dt]);
            }
        }
    }

    // rsacc[rg][r] = denom for q-row rg*16 + quad*4 + r (same lane as O rows)
#pragma unroll
    for (int rg = 0; rg < 2; ++rg) {
        float inv[4];
#pragma unroll
        for (int r = 0; r < 4; ++r) inv[r] = 1.f / rsacc[rg][r];
#pragma unroll
        for (int dt = 0; dt < 4; ++dt) {
            size_t base = ((rowoff + mbase + rg * 16 + quad * 4) << 10)
                        + (h << 6) + dt * 16 + l15;
#pragma unroll
            for (int r = 0; r < 4; ++r)
                ao[base + ((size_t)r << 10)] = f2b(O[rg][dt][r] * inv[r]);
        }
    }
}

// ---------------------------------------------------------------------------
extern "C" void kernel_launch(void* const* d_in, const int* in_sizes, int n_in,
                              void* d_out, int out_size, void* d_ws, size_t ws_size,
                              hipStream_t stream)
{
    const float* x       = (const float*)d_in[0];
    const int*   mask    = (const int*)d_in[1];
    const float* gamma   = (const float*)d_in[2];
    const float* null_kv = (const float*)d_in[3];
    const float* Wq      = (const float*)d_in[4];
    const float* Wkv     = (const float*)d_in[5];
    const float* q_scale = (const float*)d_in[6];
    const float* k_scale = (const float*)d_in[7];
    const float* Wout    = (const float*)d_in[8];

    // Workspace map (~70.07 MiB; ao aliases xn; WqT overlaps VtG tail --
    // WqT is dead after gemm<0>, before nullkv/gemm<1> write VtG):
    //   0        xn/ao   16 MiB
    //   16 MiB   q       16 MiB
    //   32 MiB   kvK     16 MiB   [tok][1024] bf16
    //   48 MiB   VtG     16.06 MiB = 4096 rows * 4112 B ([bh][d][2056] f16)
    //   VtGend-2MiB WqT  2 MiB    (inside VtG tail)
    //   VtGend   WkvT    4 MiB
    //   +4 MiB   WoutT   2 MiB
    //   +2 MiB   knull   2 KiB
    char* ws = (char*)d_ws;
    const size_t VTG_OFF  = (size_t)48u << 20;
    const size_t VTG_SIZE = (size_t)4096 * 4112;
    unsigned short* xn    = (unsigned short*)(ws);
    unsigned short* ao    = xn;                                    // reuse
    unsigned short* q     = (unsigned short*)(ws + ((size_t)16u << 20));
    unsigned short* kvK   = (unsigned short*)(ws + ((size_t)32u << 20));
    unsigned short* VtG   = (unsigned short*)(ws + VTG_OFF);
    unsigned short* WqT   = (unsigned short*)(ws + VTG_OFF + VTG_SIZE - ((size_t)2u << 20));
    unsigned short* WkvT  = (unsigned short*)(ws + VTG_OFF + VTG_SIZE);
    unsigned short* WoutT = (unsigned short*)(ws + VTG_OFF + VTG_SIZE + ((size_t)4u << 20));
    unsigned short* knull = (unsigned short*)(ws + VTG_OFF + VTG_SIZE + ((size_t)6u << 20));

    dim3 tb(32, 8);
    transpose_f2b<<<dim3(32, 32), tb, 0, stream>>>(Wq,   WqT,   1024, 1024);
    transpose_f2b<<<dim3(64, 32), tb, 0, stream>>>(Wkv,  WkvT,  1024, 2048);
    transpose_f2b<<<dim3(32, 32), tb, 0, stream>>>(Wout, WoutT, 1024, 1024);

    ln_kernel<<<8192, 256, 0, stream>>>(x, gamma, xn);

    gemm_bt<0><<<dim3(8, 64),  256, 0, stream>>>(xn, WqT, q, q_scale, nullptr,
                                                 8192, 1024, 1024, 1024);
    // nullkv after gemm<0> (WqT dead); writes VtG col 2048 + zero pad
    nullkv_kernel<<<4, 256, 0, stream>>>(null_kv, k_scale, knull, VtG);

    gemm_bt<1><<<dim3(16, 64), 256, 0, stream>>>(xn, WkvT, kvK, k_scale, VtG,
                                                 8192, 2048, 1024, 1024);

    attn_kernel<<<dim3(64, 16), 256, 0, stream>>>(q, kvK, knull, VtG, mask, ao);

    gemm_bt<2><<<dim3(8, 64), 256, 0, stream>>>(ao, WoutT, d_out, nullptr, nullptr,
                                                8192, 1024, 1024, 1024);
}